// Round 1
// baseline (259.119 us; speedup 1.0000x reference)
//
#include <hip/hip_runtime.h>
#include <hip/hip_bf16.h>

// dims
#define AB_ELEMS 50331648LL   // 128*24*16384

__device__ __forceinline__ float gelu_f(float x) {
  return 0.5f * x * (1.0f + erff(x * 0.7071067811865475f));
}

__device__ __forceinline__ float tanh_f(float x) {
  float cx = fminf(fmaxf(x, -15.f), 15.f);
  float e = __expf(2.f * cx);
  return (e - 1.f) * __builtin_amdgcn_rcpf(e + 1.f);
}

// block=256 sum; safe for back-to-back calls (leading barrier protects red)
__device__ __forceinline__ float block_sum256(float v, float* red) {
  #pragma unroll
  for (int off = 32; off > 0; off >>= 1) v += __shfl_down(v, off, 64);
  int wid = threadIdx.x >> 6;
  __syncthreads();
  if ((threadIdx.x & 63) == 0) red[wid] = v;
  __syncthreads();
  return red[0] + red[1] + red[2] + red[3];
}

// K1: enc_tok[b,s,m] = gelu(ln(pogt@We + be)); 4 rows per block, thread=m
__global__ __launch_bounds__(256) void k_encoder(
    const float* __restrict__ pogt, const float* __restrict__ We,
    const float* __restrict__ be, const float* __restrict__ lng,
    const float* __restrict__ lnb, float* __restrict__ enc_tok) {
  const int m = threadIdx.x;
  const int row0 = blockIdx.x * 4;
  __shared__ float ps[4][64];
  __shared__ float red[4];
  ps[m >> 6][m & 63] = pogt[row0 * 64 + m];
  __syncthreads();
  float x0 = be[m], x1 = x0, x2 = x0, x3 = x0;
  #pragma unroll 8
  for (int d = 0; d < 64; ++d) {
    float w = We[d * 256 + m];
    x0 = fmaf(ps[0][d], w, x0);
    x1 = fmaf(ps[1][d], w, x1);
    x2 = fmaf(ps[2][d], w, x2);
    x3 = fmaf(ps[3][d], w, x3);
  }
  const float g = lng[m], bb = lnb[m];
  float xs[4] = {x0, x1, x2, x3};
  #pragma unroll
  for (int r = 0; r < 4; ++r) {
    float mu = block_sum256(xs[r], red) * (1.f / 256.f);
    float dv = xs[r] - mu;
    float var = block_sum256(dv * dv, red) * (1.f / 256.f);
    float y = dv * rsqrtf(var + 1e-5f) * g + bb;
    enc_tok[(row0 + r) * 256 + m] = gelu_f(y);
  }
}

// K2: per-batch small chain. encoding -> predictor -> surprise -> gate ->
// mem_new (to d_out) -> hypernet h (to ws). block=b, thread=m
__global__ __launch_bounds__(256) void k_small(
    const float* __restrict__ enc_tok,
    const float* __restrict__ Wp1, const float* __restrict__ bp1,
    const float* __restrict__ Wp2, const float* __restrict__ bp2,
    const float* __restrict__ bg1, const float* __restrict__ ln_g_g,
    const float* __restrict__ ln_g_b, const float* __restrict__ Wg2,
    const float* __restrict__ bg2, const float* __restrict__ Wh1,
    const float* __restrict__ bh1, const float* __restrict__ ln_h_g,
    const float* __restrict__ ln_h_b, const float* __restrict__ Wh2,
    const float* __restrict__ bh2, float* __restrict__ mem_out,
    float* __restrict__ hout) {
  const int b = blockIdx.x;
  const int m = threadIdx.x;
  __shared__ float enc_s[256];
  __shared__ float t1_s[256];
  __shared__ float gg_s[256];
  __shared__ float mem_s[256];
  __shared__ float t3_s[128];
  __shared__ float red[4];

  // encoding = mean over S
  float acc = 0.f;
  const float* et = enc_tok + (size_t)b * 64 * 256 + m;
  #pragma unroll 8
  for (int s = 0; s < 64; ++s) acc += et[s * 256];
  const float enc = acc * (1.f / 64.f);
  enc_s[m] = enc;
  __syncthreads();

  // t1 = gelu(enc @ Wp1 + bp1)   (4-way split accumulators for ILP)
  float a0 = 0.f, a1 = 0.f, a2 = 0.f, a3 = 0.f;
  #pragma unroll 4
  for (int d = 0; d < 256; d += 4) {
    a0 = fmaf(enc_s[d + 0], Wp1[(d + 0) * 256 + m], a0);
    a1 = fmaf(enc_s[d + 1], Wp1[(d + 1) * 256 + m], a1);
    a2 = fmaf(enc_s[d + 2], Wp1[(d + 2) * 256 + m], a2);
    a3 = fmaf(enc_s[d + 3], Wp1[(d + 3) * 256 + m], a3);
  }
  t1_s[m] = gelu_f(bp1[m] + ((a0 + a1) + (a2 + a3)));
  __syncthreads();

  // predicted = t1 @ Wp2 + bp2 ; surprise
  a0 = a1 = a2 = a3 = 0.f;
  #pragma unroll 4
  for (int d = 0; d < 256; d += 4) {
    a0 = fmaf(t1_s[d + 0], Wp2[(d + 0) * 256 + m], a0);
    a1 = fmaf(t1_s[d + 1], Wp2[(d + 1) * 256 + m], a1);
    a2 = fmaf(t1_s[d + 2], Wp2[(d + 2) * 256 + m], a2);
    a3 = fmaf(t1_s[d + 3], Wp2[(d + 3) * 256 + m], a3);
  }
  const float pred = bp2[m] + ((a0 + a1) + (a2 + a3));
  const float raw = block_sum256(fabsf(pred - enc), red);
  const float surprise = fminf(fmaxf(raw, 0.f), 1.f);  // /(1+1e-8) == 1 in f32

  // gate (batch-independent: memory==0 so x0 = bg1)
  const float x0 = bg1[m];
  const float mu = block_sum256(x0, red) * (1.f / 256.f);
  const float dv = x0 - mu;
  const float var = block_sum256(dv * dv, red) * (1.f / 256.f);
  gg_s[m] = gelu_f(dv * rsqrtf(var + 1e-5f) * ln_g_g[m] + ln_g_b[m]);
  __syncthreads();
  a0 = a1 = a2 = a3 = 0.f;
  #pragma unroll 4
  for (int d = 0; d < 256; d += 4) {
    a0 = fmaf(gg_s[d + 0], Wg2[(d + 0) * 256 + m], a0);
    a1 = fmaf(gg_s[d + 1], Wg2[(d + 1) * 256 + m], a1);
    a2 = fmaf(gg_s[d + 2], Wg2[(d + 2) * 256 + m], a2);
    a3 = fmaf(gg_s[d + 3], Wg2[(d + 3) * 256 + m], a3);
  }
  const float gx = bg2[m] + ((a0 + a1) + (a2 + a3));
  const float gate = 1.f / (1.f + __expf(-gx));

  // mem_new = clip(gate*surprise*enc, -10, 10)   (memory==0)
  float mem = gate * surprise * enc;
  mem = fminf(fmaxf(mem, -10.f), 10.f);
  mem_s[m] = mem;
  mem_out[b * 256 + m] = mem;
  __syncthreads();

  // hypernet: q = mem @ Wh1 + bh1 (128) ; LN ; gelu
  float qv = 0.f;
  if (m < 128) {
    float q0 = 0.f, q1 = 0.f, q2 = 0.f, q3 = 0.f;
    #pragma unroll 4
    for (int d = 0; d < 256; d += 4) {
      q0 = fmaf(mem_s[d + 0], Wh1[(d + 0) * 128 + m], q0);
      q1 = fmaf(mem_s[d + 1], Wh1[(d + 1) * 128 + m], q1);
      q2 = fmaf(mem_s[d + 2], Wh1[(d + 2) * 128 + m], q2);
      q3 = fmaf(mem_s[d + 3], Wh1[(d + 3) * 128 + m], q3);
    }
    qv = bh1[m] + ((q0 + q1) + (q2 + q3));
  }
  const float qmu = block_sum256(m < 128 ? qv : 0.f, red) * (1.f / 128.f);
  const float qd = qv - qmu;
  const float qvar = block_sum256(m < 128 ? qd * qd : 0.f, red) * (1.f / 128.f);
  if (m < 128)
    t3_s[m] = gelu_f(qd * rsqrtf(qvar + 1e-5f) * ln_h_g[m] + ln_h_b[m]);
  __syncthreads();

  // h = gelu(t3 @ Wh2 + bh2) (64)
  if (m < 64) {
    float h0 = 0.f, h1 = 0.f;
    #pragma unroll 4
    for (int d = 0; d < 128; d += 2) {
      h0 = fmaf(t3_s[d + 0], Wh2[(d + 0) * 64 + m], h0);
      h1 = fmaf(t3_s[d + 1], Wh2[(d + 1) * 64 + m], h1);
    }
    hout[b * 64 + m] = gelu_f(bh2[m] + h0 + h1);
  }
}

// K3: out[b,l,k] = tanh(sum_d h[b,d]*W[l,d,k] + bias[l,k])
// block: one (mat, l, 128-wide k tile) x all 128 b. 256 thr, 8b x 8k micro-tile.
__global__ __launch_bounds__(256) void k_lora(
    const float* __restrict__ WA, const float* __restrict__ bA,
    const float* __restrict__ WB, const float* __restrict__ bB,
    const float* __restrict__ h, float* __restrict__ out) {
  __shared__ float hs[128 * 65];      // [b][d], stride 65 (bank spread)
  __shared__ float ws_[64 * 128];     // [d][j][kg]: w(d, kg*8+j) at d*128+j*16+kg
  const int t = threadIdx.x;
  const int bid = blockIdx.x;
  const int kt = bid & 127;           // 128 k-tiles of 128
  const int l = (bid >> 7) % 24;
  const int mat = bid / 3072;         // 0 = A, 1 = B
  const float* __restrict__ W = mat ? WB : WA;
  const float* __restrict__ bias = mat ? bB : bA;
  const int k0 = kt * 128;

  // stage h: 128x64 floats
  const float4* h4 = (const float4*)h;
  #pragma unroll
  for (int p = 0; p < 8; ++p) {
    int v = t + p * 256;              // 0..2047 float4 index
    float4 val = h4[v];
    int b = v >> 4;
    int d0 = (v & 15) << 2;
    float* dst = &hs[b * 65 + d0];
    dst[0] = val.x; dst[1] = val.y; dst[2] = val.z; dst[3] = val.w;
  }
  // stage W tile: 64 d x 128 k, interleaved [d][j][kg]
  const float* Wl = W + (size_t)l * (64 * 16384) + k0;
  #pragma unroll
  for (int p = 0; p < 8; ++p) {
    int v = t + p * 256;              // 0..2047 float4 index
    int d = v >> 5;                   // 32 float4 per row
    int c = (v & 31) << 2;            // k offset within tile (mult of 4)
    float4 val = *(const float4*)(Wl + (size_t)d * 16384 + c);
    int kgs = c >> 3;
    int j0 = c & 4;
    float* dst = &ws_[d * 128 + j0 * 16 + kgs];
    dst[0] = val.x; dst[16] = val.y; dst[32] = val.z; dst[48] = val.w;
  }
  __syncthreads();

  const int kg = t & 15;              // 16 k-groups of 8 consecutive k
  const int bg = t >> 4;              // 16 b-groups of 8 b
  float acc[8][8];
  #pragma unroll
  for (int i = 0; i < 8; ++i)
    #pragma unroll
    for (int j = 0; j < 8; ++j) acc[i][j] = 0.f;

  #pragma unroll 4
  for (int d = 0; d < 64; ++d) {
    const float* wrow = &ws_[d * 128 + kg];
    float w[8];
    #pragma unroll
    for (int j = 0; j < 8; ++j) w[j] = wrow[j * 16];
    #pragma unroll
    for (int i = 0; i < 8; ++i) {
      float hv = hs[(bg * 8 + i) * 65 + d];
      #pragma unroll
      for (int j = 0; j < 8; ++j) acc[i][j] = fmaf(hv, w[j], acc[i][j]);
    }
  }

  // epilogue: bias + tanh + store (8 consecutive k per thread)
  const float* bp = bias + (size_t)l * 16384 + k0 + kg * 8;
  float4 bv0 = *(const float4*)(bp);
  float4 bv1 = *(const float4*)(bp + 4);
  float* obase = out + (size_t)mat * AB_ELEMS + (size_t)l * 16384 + k0 + kg * 8;
  #pragma unroll
  for (int i = 0; i < 8; ++i) {
    int b = bg * 8 + i;
    float* op = obase + (size_t)b * (24 * 16384);
    float4 o0, o1;
    o0.x = tanh_f(acc[i][0] + bv0.x);
    o0.y = tanh_f(acc[i][1] + bv0.y);
    o0.z = tanh_f(acc[i][2] + bv0.z);
    o0.w = tanh_f(acc[i][3] + bv0.w);
    o1.x = tanh_f(acc[i][4] + bv1.x);
    o1.y = tanh_f(acc[i][5] + bv1.y);
    o1.z = tanh_f(acc[i][6] + bv1.z);
    o1.w = tanh_f(acc[i][7] + bv1.w);
    *(float4*)(op) = o0;
    *(float4*)(op + 4) = o1;
  }
}

extern "C" void kernel_launch(void* const* d_in, const int* in_sizes, int n_in,
                              void* d_out, int out_size, void* d_ws, size_t ws_size,
                              hipStream_t stream) {
  const float* pogt   = (const float*)d_in[0];
  const float* We     = (const float*)d_in[1];
  const float* be     = (const float*)d_in[2];
  const float* ln_e_g = (const float*)d_in[3];
  const float* ln_e_b = (const float*)d_in[4];
  const float* Wp1    = (const float*)d_in[5];
  const float* bp1    = (const float*)d_in[6];
  const float* Wp2    = (const float*)d_in[7];
  const float* bp2    = (const float*)d_in[8];
  // d_in[9] = Wg1 — unused (memory == 0 so memory@Wg1 == 0)
  const float* bg1    = (const float*)d_in[10];
  const float* ln_g_g = (const float*)d_in[11];
  const float* ln_g_b = (const float*)d_in[12];
  const float* Wg2    = (const float*)d_in[13];
  const float* bg2    = (const float*)d_in[14];
  const float* Wh1    = (const float*)d_in[15];
  const float* bh1    = (const float*)d_in[16];
  const float* ln_h_g = (const float*)d_in[17];
  const float* ln_h_b = (const float*)d_in[18];
  const float* Wh2    = (const float*)d_in[19];
  const float* bh2    = (const float*)d_in[20];
  const float* WA     = (const float*)d_in[21];
  const float* bA     = (const float*)d_in[22];
  const float* WB     = (const float*)d_in[23];
  const float* bB     = (const float*)d_in[24];

  float* out = (float*)d_out;
  float* enc_tok = (float*)d_ws;                       // 8 MB
  float* hbuf = (float*)((char*)d_ws + 8388608);       // 32 KB
  float* mem_out = out + 2 * AB_ELEMS;                 // [128,256] tail of d_out

  k_encoder<<<2048, 256, 0, stream>>>(pogt, We, be, ln_e_g, ln_e_b, enc_tok);
  k_small<<<128, 256, 0, stream>>>(enc_tok, Wp1, bp1, Wp2, bp2, bg1, ln_g_g,
                                   ln_g_b, Wg2, bg2, Wh1, bh1, ln_h_g, ln_h_b,
                                   Wh2, bh2, mem_out, hbuf);
  k_lora<<<6144, 256, 0, stream>>>(WA, bA, WB, bB, hbuf, out);
}

// Round 3
// 256.537 us; speedup vs baseline: 1.0101x; 1.0101x over previous
//
#include <hip/hip_runtime.h>
#include <hip/hip_bf16.h>

// dims
#define AB_ELEMS 50331648LL   // 128*24*16384
#define HS_STRIDE 132         // hs row stride in floats (16B-aligned, bank-spread)

typedef float f32x4 __attribute__((ext_vector_type(4)));

__device__ __forceinline__ float gelu_f(float x) {
  return 0.5f * x * (1.0f + erff(x * 0.7071067811865475f));
}

__device__ __forceinline__ float tanh_f(float x) {
  float cx = fminf(fmaxf(x, -15.f), 15.f);
  float e = __expf(2.f * cx);
  return (e - 1.f) * __builtin_amdgcn_rcpf(e + 1.f);
}

// block=256 sum; safe for back-to-back calls (leading barrier protects red)
__device__ __forceinline__ float block_sum256(float v, float* red) {
  #pragma unroll
  for (int off = 32; off > 0; off >>= 1) v += __shfl_down(v, off, 64);
  int wid = threadIdx.x >> 6;
  __syncthreads();
  if ((threadIdx.x & 63) == 0) red[wid] = v;
  __syncthreads();
  return red[0] + red[1] + red[2] + red[3];
}

// K1: enc_tok[b,s,m] = gelu(ln(pogt@We + be)); 4 rows per block, thread=m
__global__ __launch_bounds__(256) void k_encoder(
    const float* __restrict__ pogt, const float* __restrict__ We,
    const float* __restrict__ be, const float* __restrict__ lng,
    const float* __restrict__ lnb, float* __restrict__ enc_tok) {
  const int m = threadIdx.x;
  const int row0 = blockIdx.x * 4;
  __shared__ float ps[4][64];
  __shared__ float red[4];
  ps[m >> 6][m & 63] = pogt[row0 * 64 + m];
  __syncthreads();
  float x0 = be[m], x1 = x0, x2 = x0, x3 = x0;
  #pragma unroll 8
  for (int d = 0; d < 64; ++d) {
    float w = We[d * 256 + m];
    x0 = fmaf(ps[0][d], w, x0);
    x1 = fmaf(ps[1][d], w, x1);
    x2 = fmaf(ps[2][d], w, x2);
    x3 = fmaf(ps[3][d], w, x3);
  }
  const float g = lng[m], bb = lnb[m];
  float xs[4] = {x0, x1, x2, x3};
  #pragma unroll
  for (int r = 0; r < 4; ++r) {
    float mu = block_sum256(xs[r], red) * (1.f / 256.f);
    float dv = xs[r] - mu;
    float var = block_sum256(dv * dv, red) * (1.f / 256.f);
    float y = dv * rsqrtf(var + 1e-5f) * g + bb;
    enc_tok[(row0 + r) * 256 + m] = gelu_f(y);
  }
}

// K2: per-batch small chain. encoding -> predictor -> surprise -> gate ->
// mem_new (to d_out) -> hypernet h (to ws). block=b, thread=m
__global__ __launch_bounds__(256) void k_small(
    const float* __restrict__ enc_tok,
    const float* __restrict__ Wp1, const float* __restrict__ bp1,
    const float* __restrict__ Wp2, const float* __restrict__ bp2,
    const float* __restrict__ bg1, const float* __restrict__ ln_g_g,
    const float* __restrict__ ln_g_b, const float* __restrict__ Wg2,
    const float* __restrict__ bg2, const float* __restrict__ Wh1,
    const float* __restrict__ bh1, const float* __restrict__ ln_h_g,
    const float* __restrict__ ln_h_b, const float* __restrict__ Wh2,
    const float* __restrict__ bh2, float* __restrict__ mem_out,
    float* __restrict__ hout) {
  const int b = blockIdx.x;
  const int m = threadIdx.x;
  __shared__ float enc_s[256];
  __shared__ float t1_s[256];
  __shared__ float gg_s[256];
  __shared__ float mem_s[256];
  __shared__ float t3_s[128];
  __shared__ float red[4];

  // encoding = mean over S
  float acc = 0.f;
  const float* et = enc_tok + (size_t)b * 64 * 256 + m;
  #pragma unroll 8
  for (int s = 0; s < 64; ++s) acc += et[s * 256];
  const float enc = acc * (1.f / 64.f);
  enc_s[m] = enc;
  __syncthreads();

  // t1 = gelu(enc @ Wp1 + bp1)
  float a0 = 0.f, a1 = 0.f, a2 = 0.f, a3 = 0.f;
  #pragma unroll 4
  for (int d = 0; d < 256; d += 4) {
    a0 = fmaf(enc_s[d + 0], Wp1[(d + 0) * 256 + m], a0);
    a1 = fmaf(enc_s[d + 1], Wp1[(d + 1) * 256 + m], a1);
    a2 = fmaf(enc_s[d + 2], Wp1[(d + 2) * 256 + m], a2);
    a3 = fmaf(enc_s[d + 3], Wp1[(d + 3) * 256 + m], a3);
  }
  t1_s[m] = gelu_f(bp1[m] + ((a0 + a1) + (a2 + a3)));
  __syncthreads();

  // predicted = t1 @ Wp2 + bp2 ; surprise
  a0 = a1 = a2 = a3 = 0.f;
  #pragma unroll 4
  for (int d = 0; d < 256; d += 4) {
    a0 = fmaf(t1_s[d + 0], Wp2[(d + 0) * 256 + m], a0);
    a1 = fmaf(t1_s[d + 1], Wp2[(d + 1) * 256 + m], a1);
    a2 = fmaf(t1_s[d + 2], Wp2[(d + 2) * 256 + m], a2);
    a3 = fmaf(t1_s[d + 3], Wp2[(d + 3) * 256 + m], a3);
  }
  const float pred = bp2[m] + ((a0 + a1) + (a2 + a3));
  const float raw = block_sum256(fabsf(pred - enc), red);
  const float surprise = fminf(fmaxf(raw, 0.f), 1.f);

  // gate (batch-independent: memory==0 so x0 = bg1)
  const float x0 = bg1[m];
  const float mu = block_sum256(x0, red) * (1.f / 256.f);
  const float dv = x0 - mu;
  const float var = block_sum256(dv * dv, red) * (1.f / 256.f);
  gg_s[m] = gelu_f(dv * rsqrtf(var + 1e-5f) * ln_g_g[m] + ln_g_b[m]);
  __syncthreads();
  a0 = a1 = a2 = a3 = 0.f;
  #pragma unroll 4
  for (int d = 0; d < 256; d += 4) {
    a0 = fmaf(gg_s[d + 0], Wg2[(d + 0) * 256 + m], a0);
    a1 = fmaf(gg_s[d + 1], Wg2[(d + 1) * 256 + m], a1);
    a2 = fmaf(gg_s[d + 2], Wg2[(d + 2) * 256 + m], a2);
    a3 = fmaf(gg_s[d + 3], Wg2[(d + 3) * 256 + m], a3);
  }
  const float gx = bg2[m] + ((a0 + a1) + (a2 + a3));
  const float gate = 1.f / (1.f + __expf(-gx));

  // mem_new = clip(gate*surprise*enc, -10, 10)
  float mem = gate * surprise * enc;
  mem = fminf(fmaxf(mem, -10.f), 10.f);
  mem_s[m] = mem;
  mem_out[b * 256 + m] = mem;
  __syncthreads();

  // hypernet: q = mem @ Wh1 + bh1 (128) ; LN ; gelu
  float qv = 0.f;
  if (m < 128) {
    float q0 = 0.f, q1 = 0.f, q2 = 0.f, q3 = 0.f;
    #pragma unroll 4
    for (int d = 0; d < 256; d += 4) {
      q0 = fmaf(mem_s[d + 0], Wh1[(d + 0) * 128 + m], q0);
      q1 = fmaf(mem_s[d + 1], Wh1[(d + 1) * 128 + m], q1);
      q2 = fmaf(mem_s[d + 2], Wh1[(d + 2) * 128 + m], q2);
      q3 = fmaf(mem_s[d + 3], Wh1[(d + 3) * 128 + m], q3);
    }
    qv = bh1[m] + ((q0 + q1) + (q2 + q3));
  }
  const float qmu = block_sum256(m < 128 ? qv : 0.f, red) * (1.f / 128.f);
  const float qd = qv - qmu;
  const float qvar = block_sum256(m < 128 ? qd * qd : 0.f, red) * (1.f / 128.f);
  if (m < 128)
    t3_s[m] = gelu_f(qd * rsqrtf(qvar + 1e-5f) * ln_h_g[m] + ln_h_b[m]);
  __syncthreads();

  // h = gelu(t3 @ Wh2 + bh2) (64)
  if (m < 64) {
    float h0 = 0.f, h1 = 0.f;
    #pragma unroll 4
    for (int d = 0; d < 128; d += 2) {
      h0 = fmaf(t3_s[d + 0], Wh2[(d + 0) * 64 + m], h0);
      h1 = fmaf(t3_s[d + 1], Wh2[(d + 1) * 64 + m], h1);
    }
    hout[b * 64 + m] = gelu_f(bh2[m] + h0 + h1);
  }
}

// K3: out[b,l,k] = tanh(sum_d h[b,d]*W[l,d,k] + bias[l,k])
// W streams global->register (2x dwordx4/d, no LDS, no in-loop barrier).
// h transposed in LDS: hs[d][b], stride 132 -> 2x conflict-free ds_read_b128/d.
__global__ __launch_bounds__(256, 3) void k_lora(
    const float* __restrict__ WA, const float* __restrict__ bA,
    const float* __restrict__ WB, const float* __restrict__ bB,
    const float* __restrict__ h, float* __restrict__ out) {
  __shared__ float hs[64 * HS_STRIDE];   // [d][b]
  const int t = threadIdx.x;
  const int bid = blockIdx.x;
  const int kt = bid & 127;              // 128 k-tiles of 128
  const int l = (bid >> 7) % 24;
  const int mat = bid / 3072;            // 0 = A, 1 = B
  const float* __restrict__ W = mat ? WB : WA;
  const float* __restrict__ bias = mat ? bB : bA;
  const int k0 = kt * 128;

  // stage h transposed: hs[d][b] = h[b][d]   (one-time, 8 float4/thread)
  const float4* h4 = (const float4*)h;
  #pragma unroll
  for (int p = 0; p < 8; ++p) {
    int v = t + p * 256;                 // 0..2047 float4 index
    float4 val = h4[v];
    int b = v >> 4;
    int d0 = (v & 15) << 2;
    hs[(d0 + 0) * HS_STRIDE + b] = val.x;
    hs[(d0 + 1) * HS_STRIDE + b] = val.y;
    hs[(d0 + 2) * HS_STRIDE + b] = val.z;
    hs[(d0 + 3) * HS_STRIDE + b] = val.w;
  }
  __syncthreads();

  const int kg = t & 15;                 // 16 k-groups of 8 consecutive k
  const int bg = t >> 4;                 // 16 b-groups of 8 b
  const float* Wt = W + (size_t)l * (64 * 16384) + k0 + kg * 8;
  const float* hb = &hs[bg * 8];

  float acc[8][8];
  #pragma unroll
  for (int i = 0; i < 8; ++i)
    #pragma unroll
    for (int j = 0; j < 8; ++j) acc[i][j] = 0.f;

  #pragma unroll 4
  for (int d = 0; d < 64; ++d) {
    float4 w0 = *(const float4*)(Wt + (size_t)d * 16384);
    float4 w1 = *(const float4*)(Wt + (size_t)d * 16384 + 4);
    float4 hv0 = *(const float4*)(hb + d * HS_STRIDE);
    float4 hv1 = *(const float4*)(hb + d * HS_STRIDE + 4);
    float w[8] = {w0.x, w0.y, w0.z, w0.w, w1.x, w1.y, w1.z, w1.w};
    float hh[8] = {hv0.x, hv0.y, hv0.z, hv0.w, hv1.x, hv1.y, hv1.z, hv1.w};
    #pragma unroll
    for (int i = 0; i < 8; ++i)
      #pragma unroll
      for (int j = 0; j < 8; ++j) acc[i][j] = fmaf(hh[i], w[j], acc[i][j]);
  }

  // epilogue: bias + tanh + nontemporal store (8 consecutive k per thread)
  const float* bp = bias + (size_t)l * 16384 + k0 + kg * 8;
  float4 bv0 = *(const float4*)(bp);
  float4 bv1 = *(const float4*)(bp + 4);
  float* obase = out + (size_t)mat * AB_ELEMS + (size_t)l * 16384 + k0 + kg * 8;
  #pragma unroll
  for (int i = 0; i < 8; ++i) {
    int b = bg * 8 + i;
    float* op = obase + (size_t)b * (24 * 16384);
    f32x4 o0, o1;
    o0.x = tanh_f(acc[i][0] + bv0.x);
    o0.y = tanh_f(acc[i][1] + bv0.y);
    o0.z = tanh_f(acc[i][2] + bv0.z);
    o0.w = tanh_f(acc[i][3] + bv0.w);
    o1.x = tanh_f(acc[i][4] + bv1.x);
    o1.y = tanh_f(acc[i][5] + bv1.y);
    o1.z = tanh_f(acc[i][6] + bv1.z);
    o1.w = tanh_f(acc[i][7] + bv1.w);
    __builtin_nontemporal_store(o0, (f32x4*)op);
    __builtin_nontemporal_store(o1, (f32x4*)(op + 4));
  }
}

extern "C" void kernel_launch(void* const* d_in, const int* in_sizes, int n_in,
                              void* d_out, int out_size, void* d_ws, size_t ws_size,
                              hipStream_t stream) {
  const float* pogt   = (const float*)d_in[0];
  const float* We     = (const float*)d_in[1];
  const float* be     = (const float*)d_in[2];
  const float* ln_e_g = (const float*)d_in[3];
  const float* ln_e_b = (const float*)d_in[4];
  const float* Wp1    = (const float*)d_in[5];
  const float* bp1    = (const float*)d_in[6];
  const float* Wp2    = (const float*)d_in[7];
  const float* bp2    = (const float*)d_in[8];
  // d_in[9] = Wg1 — unused (memory == 0 so memory@Wg1 == 0)
  const float* bg1    = (const float*)d_in[10];
  const float* ln_g_g = (const float*)d_in[11];
  const float* ln_g_b = (const float*)d_in[12];
  const float* Wg2    = (const float*)d_in[13];
  const float* bg2    = (const float*)d_in[14];
  const float* Wh1    = (const float*)d_in[15];
  const float* bh1    = (const float*)d_in[16];
  const float* ln_h_g = (const float*)d_in[17];
  const float* ln_h_b = (const float*)d_in[18];
  const float* Wh2    = (const float*)d_in[19];
  const float* bh2    = (const float*)d_in[20];
  const float* WA     = (const float*)d_in[21];
  const float* bA     = (const float*)d_in[22];
  const float* WB     = (const float*)d_in[23];
  const float* bB     = (const float*)d_in[24];

  float* out = (float*)d_out;
  float* enc_tok = (float*)d_ws;                       // 8 MB
  float* hbuf = (float*)((char*)d_ws + 8388608);       // 32 KB
  float* mem_out = out + 2 * AB_ELEMS;                 // [128,256] tail of d_out

  k_encoder<<<2048, 256, 0, stream>>>(pogt, We, be, ln_e_g, ln_e_b, enc_tok);
  k_small<<<128, 256, 0, stream>>>(enc_tok, Wp1, bp1, Wp2, bp2, bg1, ln_g_g,
                                   ln_g_b, Wg2, bg2, Wh1, bh1, ln_h_g, ln_h_b,
                                   Wh2, bh2, mem_out, hbuf);
  k_lora<<<6144, 256, 0, stream>>>(WA, bA, WB, bB, hbuf, out);
}

// Round 4
// 178.693 us; speedup vs baseline: 1.4501x; 1.4356x over previous
//
#include <hip/hip_runtime.h>
#include <hip/hip_bf16.h>

// dims
#define AB_ELEMS 50331648LL   // 128*24*16384

typedef float f32x4 __attribute__((ext_vector_type(4)));
typedef short short8b __attribute__((ext_vector_type(8)));

__device__ __forceinline__ float gelu_f(float x) {
  return 0.5f * x * (1.0f + erff(x * 0.7071067811865475f));
}

// tanh via exp2: tanh(x) = 1 - 2/(e^{2x}+1); saturation-safe (inf/0 paths OK)
__device__ __forceinline__ float tanh_f(float x) {
  float e = exp2f(x * 2.8853900817779268f);   // e^(2x)
  float r = __builtin_amdgcn_rcpf(e + 1.f);
  return fmaf(-2.f, r, 1.f);
}

// fp32 -> bf16 bits, RNE
__device__ __forceinline__ unsigned short f2bf(float x) {
  unsigned u = __float_as_uint(x);
  u += 0x7fffu + ((u >> 16) & 1u);
  return (unsigned short)(u >> 16);
}

// block=256 sum; safe for back-to-back calls (leading barrier protects red)
__device__ __forceinline__ float block_sum256(float v, float* red) {
  #pragma unroll
  for (int off = 32; off > 0; off >>= 1) v += __shfl_down(v, off, 64);
  int wid = threadIdx.x >> 6;
  __syncthreads();
  if ((threadIdx.x & 63) == 0) red[wid] = v;
  __syncthreads();
  return red[0] + red[1] + red[2] + red[3];
}

// K1: enc_tok[b,s,m] = gelu(ln(pogt@We + be)); 4 rows per block, thread=m
__global__ __launch_bounds__(256) void k_encoder(
    const float* __restrict__ pogt, const float* __restrict__ We,
    const float* __restrict__ be, const float* __restrict__ lng,
    const float* __restrict__ lnb, float* __restrict__ enc_tok) {
  const int m = threadIdx.x;
  const int row0 = blockIdx.x * 4;
  __shared__ float ps[4][64];
  __shared__ float red[4];
  ps[m >> 6][m & 63] = pogt[row0 * 64 + m];
  __syncthreads();
  float x0 = be[m], x1 = x0, x2 = x0, x3 = x0;
  #pragma unroll 8
  for (int d = 0; d < 64; ++d) {
    float w = We[d * 256 + m];
    x0 = fmaf(ps[0][d], w, x0);
    x1 = fmaf(ps[1][d], w, x1);
    x2 = fmaf(ps[2][d], w, x2);
    x3 = fmaf(ps[3][d], w, x3);
  }
  const float g = lng[m], bb = lnb[m];
  float xs[4] = {x0, x1, x2, x3};
  #pragma unroll
  for (int r = 0; r < 4; ++r) {
    float mu = block_sum256(xs[r], red) * (1.f / 256.f);
    float dv = xs[r] - mu;
    float var = block_sum256(dv * dv, red) * (1.f / 256.f);
    float y = dv * rsqrtf(var + 1e-5f) * g + bb;
    enc_tok[(row0 + r) * 256 + m] = gelu_f(y);
  }
}

// K2: per-batch small chain. encoding -> predictor -> surprise -> gate ->
// mem_new (to d_out) -> hypernet h (bf16, to ws). block=b, thread=m
__global__ __launch_bounds__(256) void k_small(
    const float* __restrict__ enc_tok,
    const float* __restrict__ Wp1, const float* __restrict__ bp1,
    const float* __restrict__ Wp2, const float* __restrict__ bp2,
    const float* __restrict__ bg1, const float* __restrict__ ln_g_g,
    const float* __restrict__ ln_g_b, const float* __restrict__ Wg2,
    const float* __restrict__ bg2, const float* __restrict__ Wh1,
    const float* __restrict__ bh1, const float* __restrict__ ln_h_g,
    const float* __restrict__ ln_h_b, const float* __restrict__ Wh2,
    const float* __restrict__ bh2, float* __restrict__ mem_out,
    unsigned short* __restrict__ hout) {
  const int b = blockIdx.x;
  const int m = threadIdx.x;
  __shared__ float enc_s[256];
  __shared__ float t1_s[256];
  __shared__ float gg_s[256];
  __shared__ float mem_s[256];
  __shared__ float t3_s[128];
  __shared__ float red[4];

  // encoding = mean over S
  float acc = 0.f;
  const float* et = enc_tok + (size_t)b * 64 * 256 + m;
  #pragma unroll 8
  for (int s = 0; s < 64; ++s) acc += et[s * 256];
  const float enc = acc * (1.f / 64.f);
  enc_s[m] = enc;
  __syncthreads();

  // t1 = gelu(enc @ Wp1 + bp1)
  float a0 = 0.f, a1 = 0.f, a2 = 0.f, a3 = 0.f;
  #pragma unroll 4
  for (int d = 0; d < 256; d += 4) {
    a0 = fmaf(enc_s[d + 0], Wp1[(d + 0) * 256 + m], a0);
    a1 = fmaf(enc_s[d + 1], Wp1[(d + 1) * 256 + m], a1);
    a2 = fmaf(enc_s[d + 2], Wp1[(d + 2) * 256 + m], a2);
    a3 = fmaf(enc_s[d + 3], Wp1[(d + 3) * 256 + m], a3);
  }
  t1_s[m] = gelu_f(bp1[m] + ((a0 + a1) + (a2 + a3)));
  __syncthreads();

  // predicted = t1 @ Wp2 + bp2 ; surprise
  a0 = a1 = a2 = a3 = 0.f;
  #pragma unroll 4
  for (int d = 0; d < 256; d += 4) {
    a0 = fmaf(t1_s[d + 0], Wp2[(d + 0) * 256 + m], a0);
    a1 = fmaf(t1_s[d + 1], Wp2[(d + 1) * 256 + m], a1);
    a2 = fmaf(t1_s[d + 2], Wp2[(d + 2) * 256 + m], a2);
    a3 = fmaf(t1_s[d + 3], Wp2[(d + 3) * 256 + m], a3);
  }
  const float pred = bp2[m] + ((a0 + a1) + (a2 + a3));
  const float raw = block_sum256(fabsf(pred - enc), red);
  const float surprise = fminf(fmaxf(raw, 0.f), 1.f);

  // gate (batch-independent: memory==0 so x0 = bg1)
  const float x0 = bg1[m];
  const float mu = block_sum256(x0, red) * (1.f / 256.f);
  const float dv = x0 - mu;
  const float var = block_sum256(dv * dv, red) * (1.f / 256.f);
  gg_s[m] = gelu_f(dv * rsqrtf(var + 1e-5f) * ln_g_g[m] + ln_g_b[m]);
  __syncthreads();
  a0 = a1 = a2 = a3 = 0.f;
  #pragma unroll 4
  for (int d = 0; d < 256; d += 4) {
    a0 = fmaf(gg_s[d + 0], Wg2[(d + 0) * 256 + m], a0);
    a1 = fmaf(gg_s[d + 1], Wg2[(d + 1) * 256 + m], a1);
    a2 = fmaf(gg_s[d + 2], Wg2[(d + 2) * 256 + m], a2);
    a3 = fmaf(gg_s[d + 3], Wg2[(d + 3) * 256 + m], a3);
  }
  const float gx = bg2[m] + ((a0 + a1) + (a2 + a3));
  const float gate = 1.f / (1.f + __expf(-gx));

  // mem_new = clip(gate*surprise*enc, -10, 10)
  float mem = gate * surprise * enc;
  mem = fminf(fmaxf(mem, -10.f), 10.f);
  mem_s[m] = mem;
  mem_out[b * 256 + m] = mem;
  __syncthreads();

  // hypernet: q = mem @ Wh1 + bh1 (128) ; LN ; gelu
  float qv = 0.f;
  if (m < 128) {
    float q0 = 0.f, q1 = 0.f, q2 = 0.f, q3 = 0.f;
    #pragma unroll 4
    for (int d = 0; d < 256; d += 4) {
      q0 = fmaf(mem_s[d + 0], Wh1[(d + 0) * 128 + m], q0);
      q1 = fmaf(mem_s[d + 1], Wh1[(d + 1) * 128 + m], q1);
      q2 = fmaf(mem_s[d + 2], Wh1[(d + 2) * 128 + m], q2);
      q3 = fmaf(mem_s[d + 3], Wh1[(d + 3) * 128 + m], q3);
    }
    qv = bh1[m] + ((q0 + q1) + (q2 + q3));
  }
  const float qmu = block_sum256(m < 128 ? qv : 0.f, red) * (1.f / 128.f);
  const float qd = qv - qmu;
  const float qvar = block_sum256(m < 128 ? qd * qd : 0.f, red) * (1.f / 128.f);
  if (m < 128)
    t3_s[m] = gelu_f(qd * rsqrtf(qvar + 1e-5f) * ln_h_g[m] + ln_h_b[m]);
  __syncthreads();

  // h = gelu(t3 @ Wh2 + bh2) (64) -> bf16
  if (m < 64) {
    float h0 = 0.f, h1 = 0.f;
    #pragma unroll 4
    for (int d = 0; d < 128; d += 2) {
      h0 = fmaf(t3_s[d + 0], Wh2[(d + 0) * 64 + m], h0);
      h1 = fmaf(t3_s[d + 1], Wh2[(d + 1) * 64 + m], h1);
    }
    hout[b * 64 + m] = f2bf(gelu_f(bh2[m] + h0 + h1));
  }
}

// K3 (MFMA): out[b,l,k] = tanh(sum_d h[b,d]*W[l,d,k] + bias[l,k])
// GEMM: D[k, b] = A(=W^T)[k, d] @ B(=h^T)[d, b], K=64, via mfma_f32_16x16x32_bf16.
// Per block (mat, l, 128k-tile) x all 128 b. 4 waves; wave w owns 32 k.
// A-frags: 32 scalar W dwords/lane (64B-contiguous per 16-lane group), cvt bf16.
// B-frags: h bf16 (16KB, L2-resident), 16B/lane loads. No LDS, no barriers.
// D-layout (m89): col=lane&15 -> b, row=(lane>>4)*4+reg -> k => dwordx4 stores.
__global__ __launch_bounds__(256, 4) void k_lora(
    const float* __restrict__ WA, const float* __restrict__ bA,
    const float* __restrict__ WB, const float* __restrict__ bB,
    const unsigned short* __restrict__ hb, float* __restrict__ out) {
  const int t = threadIdx.x;
  const int lane = t & 63;
  const int w = t >> 6;
  const int i = lane & 15;              // A-row (k) / B-col (b) index
  const int g = lane >> 4;              // k-dim group: d = 8g + j
  const int bid = blockIdx.x;
  const int kt = bid & 127;             // 128 k-tiles of 128
  const int l = (bid >> 7) % 24;
  const int mat = bid / 3072;           // 0 = A, 1 = B
  const float* __restrict__ W = mat ? WB : WA;
  const float* __restrict__ bias = mat ? bB : bA;
  const int kb = kt * 128 + w * 32;     // wave's k base (32 wide)

  const float* Wl = W + (size_t)l * (64 * 16384);

  // A fragments afr[ks][dc]: A[k = kb + ks*16 + i][d = dc*32 + 8g + j] = W[d][k]
  short8b afr[2][2];
  #pragma unroll
  for (int ks = 0; ks < 2; ++ks) {
    #pragma unroll
    for (int dc = 0; dc < 2; ++dc) {
      const float* p = Wl + (size_t)(dc * 32 + 8 * g) * 16384 + kb + ks * 16 + i;
      #pragma unroll
      for (int j = 0; j < 8; ++j)
        afr[ks][dc][j] = (short)f2bf(p[(size_t)j * 16384]);
    }
  }

  // acc init with bias (bias is per-k, broadcast over b)
  f32x4 acc[2][8];
  #pragma unroll
  for (int ks = 0; ks < 2; ++ks) {
    f32x4 bv = *(const f32x4*)(bias + (size_t)l * 16384 + kb + ks * 16 + g * 4);
    #pragma unroll
    for (int bs = 0; bs < 8; ++bs) acc[ks][bs] = bv;
  }

  // MFMA: 8 b-subtiles x 2 k-subtiles x 2 K-chunks
  #pragma unroll
  for (int bs = 0; bs < 8; ++bs) {
    const unsigned short* hp = hb + (bs * 16 + i) * 64 + 8 * g;
    short8b b0 = *(const short8b*)(hp);        // d = 8g..8g+7
    short8b b1 = *(const short8b*)(hp + 32);   // d = 32 + 8g..
    #pragma unroll
    for (int ks = 0; ks < 2; ++ks) {
      acc[ks][bs] = __builtin_amdgcn_mfma_f32_16x16x32_bf16(afr[ks][0], b0,
                                                            acc[ks][bs], 0, 0, 0);
      acc[ks][bs] = __builtin_amdgcn_mfma_f32_16x16x32_bf16(afr[ks][1], b1,
                                                            acc[ks][bs], 0, 0, 0);
    }
  }

  // epilogue: tanh + dwordx4 nontemporal stores (4 consecutive k per lane)
  #pragma unroll
  for (int bs = 0; bs < 8; ++bs) {
    const size_t brow = (size_t)(bs * 16 + i) * (24 * 16384);
    #pragma unroll
    for (int ks = 0; ks < 2; ++ks) {
      f32x4 o;
      #pragma unroll
      for (int r = 0; r < 4; ++r) o[r] = tanh_f(acc[ks][bs][r]);
      float* op = out + (size_t)mat * AB_ELEMS + brow + (size_t)l * 16384 +
                  kb + ks * 16 + g * 4;
      __builtin_nontemporal_store(o, (f32x4*)op);
    }
  }
}

extern "C" void kernel_launch(void* const* d_in, const int* in_sizes, int n_in,
                              void* d_out, int out_size, void* d_ws, size_t ws_size,
                              hipStream_t stream) {
  const float* pogt   = (const float*)d_in[0];
  const float* We     = (const float*)d_in[1];
  const float* be     = (const float*)d_in[2];
  const float* ln_e_g = (const float*)d_in[3];
  const float* ln_e_b = (const float*)d_in[4];
  const float* Wp1    = (const float*)d_in[5];
  const float* bp1    = (const float*)d_in[6];
  const float* Wp2    = (const float*)d_in[7];
  const float* bp2    = (const float*)d_in[8];
  // d_in[9] = Wg1 — unused (memory == 0 so memory@Wg1 == 0)
  const float* bg1    = (const float*)d_in[10];
  const float* ln_g_g = (const float*)d_in[11];
  const float* ln_g_b = (const float*)d_in[12];
  const float* Wg2    = (const float*)d_in[13];
  const float* bg2    = (const float*)d_in[14];
  const float* Wh1    = (const float*)d_in[15];
  const float* bh1    = (const float*)d_in[16];
  const float* ln_h_g = (const float*)d_in[17];
  const float* ln_h_b = (const float*)d_in[18];
  const float* Wh2    = (const float*)d_in[19];
  const float* bh2    = (const float*)d_in[20];
  const float* WA     = (const float*)d_in[21];
  const float* bA     = (const float*)d_in[22];
  const float* WB     = (const float*)d_in[23];
  const float* bB     = (const float*)d_in[24];

  float* out = (float*)d_out;
  float* enc_tok = (float*)d_ws;                            // 8 MB
  unsigned short* hbuf = (unsigned short*)((char*)d_ws + 8388608);  // 16 KB bf16
  float* mem_out = out + 2 * AB_ELEMS;                      // [128,256] tail of d_out

  k_encoder<<<2048, 256, 0, stream>>>(pogt, We, be, ln_e_g, ln_e_b, enc_tok);
  k_small<<<128, 256, 0, stream>>>(enc_tok, Wp1, bp1, Wp2, bp2, bg1, ln_g_g,
                                   ln_g_b, Wg2, bg2, Wh1, bh1, ln_h_g, ln_h_b,
                                   Wh2, bh2, mem_out, hbuf);
  k_lora<<<6144, 256, 0, stream>>>(WA, bA, WB, bB, hbuf, out);
}

// Round 5
// 154.160 us; speedup vs baseline: 1.6808x; 1.1591x over previous
//
#include <hip/hip_runtime.h>
#include <hip/hip_bf16.h>

// dims
#define AB_ELEMS 50331648LL   // 128*24*16384

typedef float f32x4 __attribute__((ext_vector_type(4)));
typedef short short8b __attribute__((ext_vector_type(8)));

__device__ __forceinline__ float gelu_f(float x) {
  return 0.5f * x * (1.0f + erff(x * 0.7071067811865475f));
}

// tanh via exp2: tanh(x) = 1 - 2/(e^{2x}+1); saturation-safe (inf/0 paths OK)
__device__ __forceinline__ float tanh_f(float x) {
  float e = exp2f(x * 2.8853900817779268f);   // e^(2x)
  float r = __builtin_amdgcn_rcpf(e + 1.f);
  return fmaf(-2.f, r, 1.f);
}

// fp32 -> bf16 bits, RNE
__device__ __forceinline__ unsigned short f2bf(float x) {
  unsigned u = __float_as_uint(x);
  u += 0x7fffu + ((u >> 16) & 1u);
  return (unsigned short)(u >> 16);
}

// block=256 sum; safe for back-to-back calls (leading barrier protects red)
__device__ __forceinline__ float block_sum256(float v, float* red) {
  #pragma unroll
  for (int off = 32; off > 0; off >>= 1) v += __shfl_down(v, off, 64);
  int wid = threadIdx.x >> 6;
  __syncthreads();
  if ((threadIdx.x & 63) == 0) red[wid] = v;
  __syncthreads();
  return red[0] + red[1] + red[2] + red[3];
}

// K1: enc_tok[b,s,m] = gelu(ln(pogt@We + be)); 4 rows per block, thread=m
__global__ __launch_bounds__(256) void k_encoder(
    const float* __restrict__ pogt, const float* __restrict__ We,
    const float* __restrict__ be, const float* __restrict__ lng,
    const float* __restrict__ lnb, float* __restrict__ enc_tok) {
  const int m = threadIdx.x;
  const int row0 = blockIdx.x * 4;
  __shared__ float ps[4][64];
  __shared__ float red[4];
  ps[m >> 6][m & 63] = pogt[row0 * 64 + m];
  __syncthreads();
  float x0 = be[m], x1 = x0, x2 = x0, x3 = x0;
  #pragma unroll 8
  for (int d = 0; d < 64; ++d) {
    float w = We[d * 256 + m];
    x0 = fmaf(ps[0][d], w, x0);
    x1 = fmaf(ps[1][d], w, x1);
    x2 = fmaf(ps[2][d], w, x2);
    x3 = fmaf(ps[3][d], w, x3);
  }
  const float g = lng[m], bb = lnb[m];
  float xs[4] = {x0, x1, x2, x3};
  #pragma unroll
  for (int r = 0; r < 4; ++r) {
    float mu = block_sum256(xs[r], red) * (1.f / 256.f);
    float dv = xs[r] - mu;
    float var = block_sum256(dv * dv, red) * (1.f / 256.f);
    float y = dv * rsqrtf(var + 1e-5f) * g + bb;
    enc_tok[(row0 + r) * 256 + m] = gelu_f(y);
  }
}

// K2: per-batch small chain. encoding -> predictor -> surprise -> gate ->
// mem_new (to d_out) -> hypernet h (bf16, to ws). block=b, thread=m
__global__ __launch_bounds__(256) void k_small(
    const float* __restrict__ enc_tok,
    const float* __restrict__ Wp1, const float* __restrict__ bp1,
    const float* __restrict__ Wp2, const float* __restrict__ bp2,
    const float* __restrict__ bg1, const float* __restrict__ ln_g_g,
    const float* __restrict__ ln_g_b, const float* __restrict__ Wg2,
    const float* __restrict__ bg2, const float* __restrict__ Wh1,
    const float* __restrict__ bh1, const float* __restrict__ ln_h_g,
    const float* __restrict__ ln_h_b, const float* __restrict__ Wh2,
    const float* __restrict__ bh2, float* __restrict__ mem_out,
    unsigned short* __restrict__ hout) {
  const int b = blockIdx.x;
  const int m = threadIdx.x;
  __shared__ float enc_s[256];
  __shared__ float t1_s[256];
  __shared__ float gg_s[256];
  __shared__ float mem_s[256];
  __shared__ float t3_s[128];
  __shared__ float red[4];

  // encoding = mean over S
  float acc = 0.f;
  const float* et = enc_tok + (size_t)b * 64 * 256 + m;
  #pragma unroll 8
  for (int s = 0; s < 64; ++s) acc += et[s * 256];
  const float enc = acc * (1.f / 64.f);
  enc_s[m] = enc;
  __syncthreads();

  // t1 = gelu(enc @ Wp1 + bp1)
  float a0 = 0.f, a1 = 0.f, a2 = 0.f, a3 = 0.f;
  #pragma unroll 4
  for (int d = 0; d < 256; d += 4) {
    a0 = fmaf(enc_s[d + 0], Wp1[(d + 0) * 256 + m], a0);
    a1 = fmaf(enc_s[d + 1], Wp1[(d + 1) * 256 + m], a1);
    a2 = fmaf(enc_s[d + 2], Wp1[(d + 2) * 256 + m], a2);
    a3 = fmaf(enc_s[d + 3], Wp1[(d + 3) * 256 + m], a3);
  }
  t1_s[m] = gelu_f(bp1[m] + ((a0 + a1) + (a2 + a3)));
  __syncthreads();

  // predicted = t1 @ Wp2 + bp2 ; surprise
  a0 = a1 = a2 = a3 = 0.f;
  #pragma unroll 4
  for (int d = 0; d < 256; d += 4) {
    a0 = fmaf(t1_s[d + 0], Wp2[(d + 0) * 256 + m], a0);
    a1 = fmaf(t1_s[d + 1], Wp2[(d + 1) * 256 + m], a1);
    a2 = fmaf(t1_s[d + 2], Wp2[(d + 2) * 256 + m], a2);
    a3 = fmaf(t1_s[d + 3], Wp2[(d + 3) * 256 + m], a3);
  }
  const float pred = bp2[m] + ((a0 + a1) + (a2 + a3));
  const float raw = block_sum256(fabsf(pred - enc), red);
  const float surprise = fminf(fmaxf(raw, 0.f), 1.f);

  // gate (batch-independent: memory==0 so x0 = bg1)
  const float x0 = bg1[m];
  const float mu = block_sum256(x0, red) * (1.f / 256.f);
  const float dv = x0 - mu;
  const float var = block_sum256(dv * dv, red) * (1.f / 256.f);
  gg_s[m] = gelu_f(dv * rsqrtf(var + 1e-5f) * ln_g_g[m] + ln_g_b[m]);
  __syncthreads();
  a0 = a1 = a2 = a3 = 0.f;
  #pragma unroll 4
  for (int d = 0; d < 256; d += 4) {
    a0 = fmaf(gg_s[d + 0], Wg2[(d + 0) * 256 + m], a0);
    a1 = fmaf(gg_s[d + 1], Wg2[(d + 1) * 256 + m], a1);
    a2 = fmaf(gg_s[d + 2], Wg2[(d + 2) * 256 + m], a2);
    a3 = fmaf(gg_s[d + 3], Wg2[(d + 3) * 256 + m], a3);
  }
  const float gx = bg2[m] + ((a0 + a1) + (a2 + a3));
  const float gate = 1.f / (1.f + __expf(-gx));

  // mem_new = clip(gate*surprise*enc, -10, 10)
  float mem = gate * surprise * enc;
  mem = fminf(fmaxf(mem, -10.f), 10.f);
  mem_s[m] = mem;
  mem_out[b * 256 + m] = mem;
  __syncthreads();

  // hypernet: q = mem @ Wh1 + bh1 (128) ; LN ; gelu
  float qv = 0.f;
  if (m < 128) {
    float q0 = 0.f, q1 = 0.f, q2 = 0.f, q3 = 0.f;
    #pragma unroll 4
    for (int d = 0; d < 256; d += 4) {
      q0 = fmaf(mem_s[d + 0], Wh1[(d + 0) * 128 + m], q0);
      q1 = fmaf(mem_s[d + 1], Wh1[(d + 1) * 128 + m], q1);
      q2 = fmaf(mem_s[d + 2], Wh1[(d + 2) * 128 + m], q2);
      q3 = fmaf(mem_s[d + 3], Wh1[(d + 3) * 128 + m], q3);
    }
    qv = bh1[m] + ((q0 + q1) + (q2 + q3));
  }
  const float qmu = block_sum256(m < 128 ? qv : 0.f, red) * (1.f / 128.f);
  const float qd = qv - qmu;
  const float qvar = block_sum256(m < 128 ? qd * qd : 0.f, red) * (1.f / 128.f);
  if (m < 128)
    t3_s[m] = gelu_f(qd * rsqrtf(qvar + 1e-5f) * ln_h_g[m] + ln_h_b[m]);
  __syncthreads();

  // h = gelu(t3 @ Wh2 + bh2) (64) -> bf16
  if (m < 64) {
    float h0 = 0.f, h1 = 0.f;
    #pragma unroll 4
    for (int d = 0; d < 128; d += 2) {
      h0 = fmaf(t3_s[d + 0], Wh2[(d + 0) * 64 + m], h0);
      h1 = fmaf(t3_s[d + 1], Wh2[(d + 1) * 64 + m], h1);
    }
    hout[b * 64 + m] = f2bf(gelu_f(bh2[m] + h0 + h1));
  }
}

// K3 (MFMA): out[b,l,k] = tanh(sum_d h[b,d]*W[l,d,k] + bias[l,k])
// GEMM: D[k, b] = A(=W^T)[k, d] @ B(=h^T)[d, b], K=64, via mfma_f32_16x16x32_bf16.
// Epilogue: per-wave LDS transpose (rotated-chunk swizzle, b128-aligned,
// uniform bank load) so every global store writes full 128B lines:
// lane = b_row*8 + k4 -> 8 rows x 128B contiguous per dwordx4 store instr.
__global__ __launch_bounds__(256, 4) void k_lora(
    const float* __restrict__ WA, const float* __restrict__ bA,
    const float* __restrict__ WB, const float* __restrict__ bB,
    const unsigned short* __restrict__ hb, float* __restrict__ out) {
  __shared__ f32x4 xp[4][32][8];        // [wave][b_row][k-chunk] = 16 KB
  const int t = threadIdx.x;
  const int lane = t & 63;
  const int w = t >> 6;
  const int i = lane & 15;              // A-row (k) / B-col (b) index
  const int g = lane >> 4;              // k-dim group: d = 8g + j
  const int bid = blockIdx.x;
  const int kt = bid & 127;             // 128 k-tiles of 128
  const int l = (bid >> 7) % 24;
  const int mat = bid / 3072;           // 0 = A, 1 = B
  const float* __restrict__ W = mat ? WB : WA;
  const float* __restrict__ bias = mat ? bB : bA;
  const int kb = kt * 128 + w * 32;     // wave's k base (32 wide)

  const float* Wl = W + (size_t)l * (64 * 16384);

  // A fragments afr[ks][dc]: A[k = kb + ks*16 + i][d = dc*32 + 8g + j] = W[d][k]
  short8b afr[2][2];
  #pragma unroll
  for (int ks = 0; ks < 2; ++ks) {
    #pragma unroll
    for (int dc = 0; dc < 2; ++dc) {
      const float* p = Wl + (size_t)(dc * 32 + 8 * g) * 16384 + kb + ks * 16 + i;
      #pragma unroll
      for (int j = 0; j < 8; ++j)
        afr[ks][dc][j] = (short)f2bf(p[(size_t)j * 16384]);
    }
  }

  // acc init with bias (bias is per-k, broadcast over b)
  f32x4 acc[2][8];
  #pragma unroll
  for (int ks = 0; ks < 2; ++ks) {
    f32x4 bv = *(const f32x4*)(bias + (size_t)l * 16384 + kb + ks * 16 + g * 4);
    #pragma unroll
    for (int bs = 0; bs < 8; ++bs) acc[ks][bs] = bv;
  }

  // MFMA: 8 b-subtiles x 2 k-subtiles x 2 K-chunks
  #pragma unroll
  for (int bs = 0; bs < 8; ++bs) {
    const unsigned short* hp = hb + (bs * 16 + i) * 64 + 8 * g;
    short8b b0 = *(const short8b*)(hp);        // d = 8g..8g+7
    short8b b1 = *(const short8b*)(hp + 32);   // d = 32 + 8g..
    #pragma unroll
    for (int ks = 0; ks < 2; ++ks) {
      acc[ks][bs] = __builtin_amdgcn_mfma_f32_16x16x32_bf16(afr[ks][0], b0,
                                                            acc[ks][bs], 0, 0, 0);
      acc[ks][bs] = __builtin_amdgcn_mfma_f32_16x16x32_bf16(afr[ks][1], b1,
                                                            acc[ks][bs], 0, 0, 0);
    }
  }

  // epilogue: tanh -> per-wave LDS transpose -> full-line coalesced stores.
  // D layout (m89): reg r of acc[ks][bs] = (k_local = ks*16+g*4+r, b = bs*16+i).
  // Chunk c covers b_global in [32c, 32c+32).
  const int r3 = lane >> 3;             // store-phase b sub-row
  const int k4 = lane & 7;              // store-phase k chunk (4 floats)
  #pragma unroll
  for (int c = 0; c < 4; ++c) {
    #pragma unroll
    for (int half = 0; half < 2; ++half) {
      const int bs = 2 * c + half;
      const int b_c = half * 16 + i;    // row within chunk, 0..31
      #pragma unroll
      for (int ks = 0; ks < 2; ++ks) {
        f32x4 o;
        #pragma unroll
        for (int r = 0; r < 4; ++r) o[r] = tanh_f(acc[ks][bs][r]);
        xp[w][b_c][((ks * 4 + g) + b_c) & 7] = o;   // rotated chunk
      }
    }
    __syncthreads();
    #pragma unroll
    for (int sub = 0; sub < 4; ++sub) {
      const int row = sub * 8 + r3;     // b row within chunk
      f32x4 v = xp[w][row][(k4 + row) & 7];
      const size_t bg2 = (size_t)(c * 32 + row);
      float* op = out + (size_t)mat * AB_ELEMS + bg2 * (24 * 16384) +
                  (size_t)l * 16384 + kb + k4 * 4;
      __builtin_nontemporal_store(v, (f32x4*)op);
    }
    __syncthreads();
  }
}

extern "C" void kernel_launch(void* const* d_in, const int* in_sizes, int n_in,
                              void* d_out, int out_size, void* d_ws, size_t ws_size,
                              hipStream_t stream) {
  const float* pogt   = (const float*)d_in[0];
  const float* We     = (const float*)d_in[1];
  const float* be     = (const float*)d_in[2];
  const float* ln_e_g = (const float*)d_in[3];
  const float* ln_e_b = (const float*)d_in[4];
  const float* Wp1    = (const float*)d_in[5];
  const float* bp1    = (const float*)d_in[6];
  const float* Wp2    = (const float*)d_in[7];
  const float* bp2    = (const float*)d_in[8];
  // d_in[9] = Wg1 — unused (memory == 0 so memory@Wg1 == 0)
  const float* bg1    = (const float*)d_in[10];
  const float* ln_g_g = (const float*)d_in[11];
  const float* ln_g_b = (const float*)d_in[12];
  const float* Wg2    = (const float*)d_in[13];
  const float* bg2    = (const float*)d_in[14];
  const float* Wh1    = (const float*)d_in[15];
  const float* bh1    = (const float*)d_in[16];
  const float* ln_h_g = (const float*)d_in[17];
  const float* ln_h_b = (const float*)d_in[18];
  const float* Wh2    = (const float*)d_in[19];
  const float* bh2    = (const float*)d_in[20];
  const float* WA     = (const float*)d_in[21];
  const float* bA     = (const float*)d_in[22];
  const float* WB     = (const float*)d_in[23];
  const float* bB     = (const float*)d_in[24];

  float* out = (float*)d_out;
  float* enc_tok = (float*)d_ws;                            // 8 MB
  unsigned short* hbuf = (unsigned short*)((char*)d_ws + 8388608);  // 16 KB bf16
  float* mem_out = out + 2 * AB_ELEMS;                      // [128,256] tail of d_out

  k_encoder<<<2048, 256, 0, stream>>>(pogt, We, be, ln_e_g, ln_e_b, enc_tok);
  k_small<<<128, 256, 0, stream>>>(enc_tok, Wp1, bp1, Wp2, bp2, bg1, ln_g_g,
                                   ln_g_b, Wg2, bg2, Wh1, bh1, ln_h_g, ln_h_b,
                                   Wh2, bh2, mem_out, hbuf);
  k_lora<<<6144, 256, 0, stream>>>(WA, bA, WB, bB, hbuf, out);
}

// Round 6
// 153.537 us; speedup vs baseline: 1.6877x; 1.0041x over previous
//
#include <hip/hip_runtime.h>
#include <hip/hip_bf16.h>

// dims
#define AB_ELEMS 50331648LL   // 128*24*16384

typedef float f32x4 __attribute__((ext_vector_type(4)));
typedef short short8b __attribute__((ext_vector_type(8)));

__device__ __forceinline__ float gelu_f(float x) {
  return 0.5f * x * (1.0f + erff(x * 0.7071067811865475f));
}

// tanh via exp2: tanh(x) = 1 - 2/(e^{2x}+1); saturation-safe (inf/0 paths OK)
__device__ __forceinline__ float tanh_f(float x) {
  float e = exp2f(x * 2.8853900817779268f);   // e^(2x)
  float r = __builtin_amdgcn_rcpf(e + 1.f);
  return fmaf(-2.f, r, 1.f);
}

// fp32 -> bf16 bits, RNE
__device__ __forceinline__ unsigned short f2bf(float x) {
  unsigned u = __float_as_uint(x);
  u += 0x7fffu + ((u >> 16) & 1u);
  return (unsigned short)(u >> 16);
}

// block=256 sum; safe for back-to-back calls (leading barrier protects red)
__device__ __forceinline__ float block_sum256(float v, float* red) {
  #pragma unroll
  for (int off = 32; off > 0; off >>= 1) v += __shfl_down(v, off, 64);
  int wid = threadIdx.x >> 6;
  __syncthreads();
  if ((threadIdx.x & 63) == 0) red[wid] = v;
  __syncthreads();
  return red[0] + red[1] + red[2] + red[3];
}

// K1: enc_tok[b,s,m] = gelu(ln(pogt@We + be)); 4 rows per block, thread=m
__global__ __launch_bounds__(256) void k_encoder(
    const float* __restrict__ pogt, const float* __restrict__ We,
    const float* __restrict__ be, const float* __restrict__ lng,
    const float* __restrict__ lnb, float* __restrict__ enc_tok) {
  const int m = threadIdx.x;
  const int row0 = blockIdx.x * 4;
  __shared__ float ps[4][64];
  __shared__ float red[4];
  ps[m >> 6][m & 63] = pogt[row0 * 64 + m];
  __syncthreads();
  float x0 = be[m], x1 = x0, x2 = x0, x3 = x0;
  #pragma unroll 8
  for (int d = 0; d < 64; ++d) {
    float w = We[d * 256 + m];
    x0 = fmaf(ps[0][d], w, x0);
    x1 = fmaf(ps[1][d], w, x1);
    x2 = fmaf(ps[2][d], w, x2);
    x3 = fmaf(ps[3][d], w, x3);
  }
  const float g = lng[m], bb = lnb[m];
  float xs[4] = {x0, x1, x2, x3};
  #pragma unroll
  for (int r = 0; r < 4; ++r) {
    float mu = block_sum256(xs[r], red) * (1.f / 256.f);
    float dv = xs[r] - mu;
    float var = block_sum256(dv * dv, red) * (1.f / 256.f);
    float y = dv * rsqrtf(var + 1e-5f) * g + bb;
    enc_tok[(row0 + r) * 256 + m] = gelu_f(y);
  }
}

// K2: per-batch small chain. encoding -> predictor -> surprise -> gate ->
// mem_new (to d_out) -> hypernet h (bf16, to ws). block=b, thread=m
__global__ __launch_bounds__(256) void k_small(
    const float* __restrict__ enc_tok,
    const float* __restrict__ Wp1, const float* __restrict__ bp1,
    const float* __restrict__ Wp2, const float* __restrict__ bp2,
    const float* __restrict__ bg1, const float* __restrict__ ln_g_g,
    const float* __restrict__ ln_g_b, const float* __restrict__ Wg2,
    const float* __restrict__ bg2, const float* __restrict__ Wh1,
    const float* __restrict__ bh1, const float* __restrict__ ln_h_g,
    const float* __restrict__ ln_h_b, const float* __restrict__ Wh2,
    const float* __restrict__ bh2, float* __restrict__ mem_out,
    unsigned short* __restrict__ hout) {
  const int b = blockIdx.x;
  const int m = threadIdx.x;
  __shared__ float enc_s[256];
  __shared__ float t1_s[256];
  __shared__ float gg_s[256];
  __shared__ float mem_s[256];
  __shared__ float t3_s[128];
  __shared__ float red[4];

  // encoding = mean over S
  float acc = 0.f;
  const float* et = enc_tok + (size_t)b * 64 * 256 + m;
  #pragma unroll 8
  for (int s = 0; s < 64; ++s) acc += et[s * 256];
  const float enc = acc * (1.f / 64.f);
  enc_s[m] = enc;
  __syncthreads();

  // t1 = gelu(enc @ Wp1 + bp1)
  float a0 = 0.f, a1 = 0.f, a2 = 0.f, a3 = 0.f;
  #pragma unroll 4
  for (int d = 0; d < 256; d += 4) {
    a0 = fmaf(enc_s[d + 0], Wp1[(d + 0) * 256 + m], a0);
    a1 = fmaf(enc_s[d + 1], Wp1[(d + 1) * 256 + m], a1);
    a2 = fmaf(enc_s[d + 2], Wp1[(d + 2) * 256 + m], a2);
    a3 = fmaf(enc_s[d + 3], Wp1[(d + 3) * 256 + m], a3);
  }
  t1_s[m] = gelu_f(bp1[m] + ((a0 + a1) + (a2 + a3)));
  __syncthreads();

  // predicted = t1 @ Wp2 + bp2 ; surprise
  a0 = a1 = a2 = a3 = 0.f;
  #pragma unroll 4
  for (int d = 0; d < 256; d += 4) {
    a0 = fmaf(t1_s[d + 0], Wp2[(d + 0) * 256 + m], a0);
    a1 = fmaf(t1_s[d + 1], Wp2[(d + 1) * 256 + m], a1);
    a2 = fmaf(t1_s[d + 2], Wp2[(d + 2) * 256 + m], a2);
    a3 = fmaf(t1_s[d + 3], Wp2[(d + 3) * 256 + m], a3);
  }
  const float pred = bp2[m] + ((a0 + a1) + (a2 + a3));
  const float raw = block_sum256(fabsf(pred - enc), red);
  const float surprise = fminf(fmaxf(raw, 0.f), 1.f);

  // gate (batch-independent: memory==0 so x0 = bg1)
  const float x0 = bg1[m];
  const float mu = block_sum256(x0, red) * (1.f / 256.f);
  const float dv = x0 - mu;
  const float var = block_sum256(dv * dv, red) * (1.f / 256.f);
  gg_s[m] = gelu_f(dv * rsqrtf(var + 1e-5f) * ln_g_g[m] + ln_g_b[m]);
  __syncthreads();
  a0 = a1 = a2 = a3 = 0.f;
  #pragma unroll 4
  for (int d = 0; d < 256; d += 4) {
    a0 = fmaf(gg_s[d + 0], Wg2[(d + 0) * 256 + m], a0);
    a1 = fmaf(gg_s[d + 1], Wg2[(d + 1) * 256 + m], a1);
    a2 = fmaf(gg_s[d + 2], Wg2[(d + 2) * 256 + m], a2);
    a3 = fmaf(gg_s[d + 3], Wg2[(d + 3) * 256 + m], a3);
  }
  const float gx = bg2[m] + ((a0 + a1) + (a2 + a3));
  const float gate = 1.f / (1.f + __expf(-gx));

  // mem_new = clip(gate*surprise*enc, -10, 10)
  float mem = gate * surprise * enc;
  mem = fminf(fmaxf(mem, -10.f), 10.f);
  mem_s[m] = mem;
  mem_out[b * 256 + m] = mem;
  __syncthreads();

  // hypernet: q = mem @ Wh1 + bh1 (128) ; LN ; gelu
  float qv = 0.f;
  if (m < 128) {
    float q0 = 0.f, q1 = 0.f, q2 = 0.f, q3 = 0.f;
    #pragma unroll 4
    for (int d = 0; d < 256; d += 4) {
      q0 = fmaf(mem_s[d + 0], Wh1[(d + 0) * 128 + m], q0);
      q1 = fmaf(mem_s[d + 1], Wh1[(d + 1) * 128 + m], q1);
      q2 = fmaf(mem_s[d + 2], Wh1[(d + 2) * 128 + m], q2);
      q3 = fmaf(mem_s[d + 3], Wh1[(d + 3) * 128 + m], q3);
    }
    qv = bh1[m] + ((q0 + q1) + (q2 + q3));
  }
  const float qmu = block_sum256(m < 128 ? qv : 0.f, red) * (1.f / 128.f);
  const float qd = qv - qmu;
  const float qvar = block_sum256(m < 128 ? qd * qd : 0.f, red) * (1.f / 128.f);
  if (m < 128)
    t3_s[m] = gelu_f(qd * rsqrtf(qvar + 1e-5f) * ln_h_g[m] + ln_h_b[m]);
  __syncthreads();

  // h = gelu(t3 @ Wh2 + bh2) (64) -> bf16
  if (m < 64) {
    float h0 = 0.f, h1 = 0.f;
    #pragma unroll 4
    for (int d = 0; d < 128; d += 2) {
      h0 = fmaf(t3_s[d + 0], Wh2[(d + 0) * 64 + m], h0);
      h1 = fmaf(t3_s[d + 1], Wh2[(d + 1) * 64 + m], h1);
    }
    hout[b * 64 + m] = f2bf(gelu_f(bh2[m] + h0 + h1));
  }
}

// K3 (MFMA): out[b,l,k] = tanh(sum_d h[b,d]*W[l,d,k] + bias[l,k])
// GEMM: D[k, b] = A(=W^T)[k, d] @ B(=h^T)[d, b], K=64, mfma_f32_16x16x32_bf16.
// Two b-half passes (acc 32 regs each). Epilogue: BLOCK-level LDS transpose
// (stride-33 f32x4, bank-balanced) -> each store instr writes 2 rows x 512 B
// fully contiguous (whole 128-k extent of the block per b-row).
__global__ __launch_bounds__(256, 4) void k_lora(
    const float* __restrict__ WA, const float* __restrict__ bA,
    const float* __restrict__ WB, const float* __restrict__ bB,
    const unsigned short* __restrict__ hb, float* __restrict__ out) {
  __shared__ f32x4 xp[64 * 33];         // 33.8 KB: [b_row][k_chunk], stride 33
  const int t = threadIdx.x;
  const int lane = t & 63;
  const int w = t >> 6;
  const int i = lane & 15;              // A-row (k) / B-col (b) index
  const int g = lane >> 4;              // k-dim group: d = 8g + j
  const int bid = blockIdx.x;
  const int kt = bid & 127;             // 128 k-tiles of 128
  const int l = (bid >> 7) % 24;
  const int mat = bid / 3072;           // 0 = A, 1 = B
  const float* __restrict__ W = mat ? WB : WA;
  const float* __restrict__ bias = mat ? bB : bA;
  const int kb_blk = kt * 128;          // block's k base (128 wide)
  const int kb = kb_blk + w * 32;       // wave's k base (32 wide)

  const float* Wl = W + (size_t)l * (64 * 16384);

  // A fragments afr[ks][dc]: A[k = kb + ks*16 + i][d = dc*32 + 8g + j] = W[d][k]
  short8b afr[2][2];
  #pragma unroll
  for (int ks = 0; ks < 2; ++ks) {
    #pragma unroll
    for (int dc = 0; dc < 2; ++dc) {
      const float* p = Wl + (size_t)(dc * 32 + 8 * g) * 16384 + kb + ks * 16 + i;
      #pragma unroll
      for (int j = 0; j < 8; ++j)
        afr[ks][dc][j] = (short)f2bf(p[(size_t)j * 16384]);
    }
  }

  // bias (per-k, broadcast over b); hoisted across passes
  f32x4 bv[2];
  #pragma unroll
  for (int ks = 0; ks < 2; ++ks)
    bv[ks] = *(const f32x4*)(bias + (size_t)l * 16384 + kb + ks * 16 + g * 4);

  // store-phase indexing
  const int kc = lane & 31;             // k chunk 0..31 (whole block k-extent)
  const int rsub = lane >> 5;           // 0/1: row within pair

  #pragma unroll
  for (int p = 0; p < 2; ++p) {
    // ---- compute pass p: b in [p*64, p*64+64) ----
    f32x4 acc[2][4];
    #pragma unroll
    for (int ks = 0; ks < 2; ++ks)
      #pragma unroll
      for (int bs = 0; bs < 4; ++bs) acc[ks][bs] = bv[ks];

    #pragma unroll
    for (int bs = 0; bs < 4; ++bs) {
      const unsigned short* hp = hb + (p * 64 + bs * 16 + i) * 64 + 8 * g;
      short8b b0 = *(const short8b*)(hp);        // d = 8g..8g+7
      short8b b1 = *(const short8b*)(hp + 32);   // d = 32 + 8g..
      #pragma unroll
      for (int ks = 0; ks < 2; ++ks) {
        acc[ks][bs] = __builtin_amdgcn_mfma_f32_16x16x32_bf16(afr[ks][0], b0,
                                                              acc[ks][bs], 0, 0, 0);
        acc[ks][bs] = __builtin_amdgcn_mfma_f32_16x16x32_bf16(afr[ks][1], b1,
                                                              acc[ks][bs], 0, 0, 0);
      }
    }

    // ---- epilogue pass p ----
    __syncthreads();                    // buffer free (prev pass reads done)
    #pragma unroll
    for (int ks = 0; ks < 2; ++ks) {
      #pragma unroll
      for (int bs = 0; bs < 4; ++bs) {
        f32x4 o;
        #pragma unroll
        for (int r = 0; r < 4; ++r) o[r] = tanh_f(acc[ks][bs][r]);
        // row = bs*16 + i (0..63), chunk = w*8 + ks*4 + g (0..31)
        xp[(bs * 16 + i) * 33 + (w * 8 + ks * 4 + g)] = o;
      }
    }
    __syncthreads();
    // read + store: wave w handles rows [w*16, w*16+16), 2 rows per instr,
    // each 32-lane half writes 512 B contiguous (kc*16B within the row).
    #pragma unroll
    for (int j = 0; j < 8; ++j) {
      const int row = w * 16 + 2 * j + rsub;
      f32x4 v = xp[row * 33 + kc];
      const size_t b_glob = (size_t)(p * 64 + row);
      float* op = out + (size_t)mat * AB_ELEMS + b_glob * (24 * 16384) +
                  (size_t)l * 16384 + kb_blk + kc * 4;
      __builtin_nontemporal_store(v, (f32x4*)op);
    }
  }
}

extern "C" void kernel_launch(void* const* d_in, const int* in_sizes, int n_in,
                              void* d_out, int out_size, void* d_ws, size_t ws_size,
                              hipStream_t stream) {
  const float* pogt   = (const float*)d_in[0];
  const float* We     = (const float*)d_in[1];
  const float* be     = (const float*)d_in[2];
  const float* ln_e_g = (const float*)d_in[3];
  const float* ln_e_b = (const float*)d_in[4];
  const float* Wp1    = (const float*)d_in[5];
  const float* bp1    = (const float*)d_in[6];
  const float* Wp2    = (const float*)d_in[7];
  const float* bp2    = (const float*)d_in[8];
  // d_in[9] = Wg1 — unused (memory == 0 so memory@Wg1 == 0)
  const float* bg1    = (const float*)d_in[10];
  const float* ln_g_g = (const float*)d_in[11];
  const float* ln_g_b = (const float*)d_in[12];
  const float* Wg2    = (const float*)d_in[13];
  const float* bg2    = (const float*)d_in[14];
  const float* Wh1    = (const float*)d_in[15];
  const float* bh1    = (const float*)d_in[16];
  const float* ln_h_g = (const float*)d_in[17];
  const float* ln_h_b = (const float*)d_in[18];
  const float* Wh2    = (const float*)d_in[19];
  const float* bh2    = (const float*)d_in[20];
  const float* WA     = (const float*)d_in[21];
  const float* bA     = (const float*)d_in[22];
  const float* WB     = (const float*)d_in[23];
  const float* bB     = (const float*)d_in[24];

  float* out = (float*)d_out;
  float* enc_tok = (float*)d_ws;                            // 8 MB
  unsigned short* hbuf = (unsigned short*)((char*)d_ws + 8388608);  // 16 KB bf16
  float* mem_out = out + 2 * AB_ELEMS;                      // [128,256] tail of d_out

  k_encoder<<<2048, 256, 0, stream>>>(pogt, We, be, ln_e_g, ln_e_b, enc_tok);
  k_small<<<128, 256, 0, stream>>>(enc_tok, Wp1, bp1, Wp2, bp2, bg1, ln_g_g,
                                   ln_g_b, Wg2, bg2, Wh1, bh1, ln_h_g, ln_h_b,
                                   Wh2, bh2, mem_out, hbuf);
  k_lora<<<6144, 256, 0, stream>>>(WA, bA, WB, bB, hbuf, out);
}

// Round 8
// 149.529 us; speedup vs baseline: 1.7329x; 1.0268x over previous
//
#include <hip/hip_runtime.h>
#include <hip/hip_bf16.h>

// dims
#define AB_ELEMS 50331648LL   // 128*24*16384

typedef float f32x4 __attribute__((ext_vector_type(4)));
typedef short short8b __attribute__((ext_vector_type(8)));

__device__ __forceinline__ float gelu_f(float x) {
  return 0.5f * x * (1.0f + erff(x * 0.7071067811865475f));
}

// tanh via exp2: tanh(x) = 1 - 2/(e^{2x}+1); saturation-safe (inf/0 paths OK)
__device__ __forceinline__ float tanh_f(float x) {
  float e = exp2f(x * 2.8853900817779268f);   // e^(2x)
  float r = __builtin_amdgcn_rcpf(e + 1.f);
  return fmaf(-2.f, r, 1.f);
}

// fp32 -> bf16 bits, RNE
__device__ __forceinline__ unsigned short f2bf(float x) {
  unsigned u = __float_as_uint(x);
  u += 0x7fffu + ((u >> 16) & 1u);
  return (unsigned short)(u >> 16);
}

// block=256 sum; safe for back-to-back calls (leading barrier protects red)
__device__ __forceinline__ float block_sum256(float v, float* red) {
  #pragma unroll
  for (int off = 32; off > 0; off >>= 1) v += __shfl_down(v, off, 64);
  int wid = threadIdx.x >> 6;
  __syncthreads();
  if ((threadIdx.x & 63) == 0) red[wid] = v;
  __syncthreads();
  return red[0] + red[1] + red[2] + red[3];
}

// K1: enc_tok[b,s,m] = gelu(ln(pogt@We + be)); 4 rows per block, thread=m
__global__ __launch_bounds__(256) void k_encoder(
    const float* __restrict__ pogt, const float* __restrict__ We,
    const float* __restrict__ be, const float* __restrict__ lng,
    const float* __restrict__ lnb, float* __restrict__ enc_tok) {
  const int m = threadIdx.x;
  const int row0 = blockIdx.x * 4;
  __shared__ float ps[4][64];
  __shared__ float red[4];
  ps[m >> 6][m & 63] = pogt[row0 * 64 + m];
  __syncthreads();
  float x0 = be[m], x1 = x0, x2 = x0, x3 = x0;
  #pragma unroll 8
  for (int d = 0; d < 64; ++d) {
    float w = We[d * 256 + m];
    x0 = fmaf(ps[0][d], w, x0);
    x1 = fmaf(ps[1][d], w, x1);
    x2 = fmaf(ps[2][d], w, x2);
    x3 = fmaf(ps[3][d], w, x3);
  }
  const float g = lng[m], bb = lnb[m];
  float xs[4] = {x0, x1, x2, x3};
  #pragma unroll
  for (int r = 0; r < 4; ++r) {
    float mu = block_sum256(xs[r], red) * (1.f / 256.f);
    float dv = xs[r] - mu;
    float var = block_sum256(dv * dv, red) * (1.f / 256.f);
    float y = dv * rsqrtf(var + 1e-5f) * g + bb;
    enc_tok[(row0 + r) * 256 + m] = gelu_f(y);
  }
}

// K2: per-batch small chain. encoding -> predictor -> surprise -> gate ->
// mem_new (to d_out) -> hypernet h (bf16, to ws). block=b, thread=m
__global__ __launch_bounds__(256) void k_small(
    const float* __restrict__ enc_tok,
    const float* __restrict__ Wp1, const float* __restrict__ bp1,
    const float* __restrict__ Wp2, const float* __restrict__ bp2,
    const float* __restrict__ bg1, const float* __restrict__ ln_g_g,
    const float* __restrict__ ln_g_b, const float* __restrict__ Wg2,
    const float* __restrict__ bg2, const float* __restrict__ Wh1,
    const float* __restrict__ bh1, const float* __restrict__ ln_h_g,
    const float* __restrict__ ln_h_b, const float* __restrict__ Wh2,
    const float* __restrict__ bh2, float* __restrict__ mem_out,
    unsigned short* __restrict__ hout) {
  const int b = blockIdx.x;
  const int m = threadIdx.x;
  __shared__ float enc_s[256];
  __shared__ float t1_s[256];
  __shared__ float gg_s[256];
  __shared__ float mem_s[256];
  __shared__ float t3_s[128];
  __shared__ float red[4];

  // encoding = mean over S
  float acc = 0.f;
  const float* et = enc_tok + (size_t)b * 64 * 256 + m;
  #pragma unroll 8
  for (int s = 0; s < 64; ++s) acc += et[s * 256];
  const float enc = acc * (1.f / 64.f);
  enc_s[m] = enc;
  __syncthreads();

  // t1 = gelu(enc @ Wp1 + bp1)
  float a0 = 0.f, a1 = 0.f, a2 = 0.f, a3 = 0.f;
  #pragma unroll 4
  for (int d = 0; d < 256; d += 4) {
    a0 = fmaf(enc_s[d + 0], Wp1[(d + 0) * 256 + m], a0);
    a1 = fmaf(enc_s[d + 1], Wp1[(d + 1) * 256 + m], a1);
    a2 = fmaf(enc_s[d + 2], Wp1[(d + 2) * 256 + m], a2);
    a3 = fmaf(enc_s[d + 3], Wp1[(d + 3) * 256 + m], a3);
  }
  t1_s[m] = gelu_f(bp1[m] + ((a0 + a1) + (a2 + a3)));
  __syncthreads();

  // predicted = t1 @ Wp2 + bp2 ; surprise
  a0 = a1 = a2 = a3 = 0.f;
  #pragma unroll 4
  for (int d = 0; d < 256; d += 4) {
    a0 = fmaf(t1_s[d + 0], Wp2[(d + 0) * 256 + m], a0);
    a1 = fmaf(t1_s[d + 1], Wp2[(d + 1) * 256 + m], a1);
    a2 = fmaf(t1_s[d + 2], Wp2[(d + 2) * 256 + m], a2);
    a3 = fmaf(t1_s[d + 3], Wp2[(d + 3) * 256 + m], a3);
  }
  const float pred = bp2[m] + ((a0 + a1) + (a2 + a3));
  const float raw = block_sum256(fabsf(pred - enc), red);
  const float surprise = fminf(fmaxf(raw, 0.f), 1.f);

  // gate (batch-independent: memory==0 so x0 = bg1)
  const float x0 = bg1[m];
  const float mu = block_sum256(x0, red) * (1.f / 256.f);
  const float dv = x0 - mu;
  const float var = block_sum256(dv * dv, red) * (1.f / 256.f);
  gg_s[m] = gelu_f(dv * rsqrtf(var + 1e-5f) * ln_g_g[m] + ln_g_b[m]);
  __syncthreads();
  a0 = a1 = a2 = a3 = 0.f;
  #pragma unroll 4
  for (int d = 0; d < 256; d += 4) {
    a0 = fmaf(gg_s[d + 0], Wg2[(d + 0) * 256 + m], a0);
    a1 = fmaf(gg_s[d + 1], Wg2[(d + 1) * 256 + m], a1);
    a2 = fmaf(gg_s[d + 2], Wg2[(d + 2) * 256 + m], a2);
    a3 = fmaf(gg_s[d + 3], Wg2[(d + 3) * 256 + m], a3);
  }
  const float gx = bg2[m] + ((a0 + a1) + (a2 + a3));
  const float gate = 1.f / (1.f + __expf(-gx));

  // mem_new = clip(gate*surprise*enc, -10, 10)
  float mem = gate * surprise * enc;
  mem = fminf(fmaxf(mem, -10.f), 10.f);
  mem_s[m] = mem;
  mem_out[b * 256 + m] = mem;
  __syncthreads();

  // hypernet: q = mem @ Wh1 + bh1 (128) ; LN ; gelu
  float qv = 0.f;
  if (m < 128) {
    float q0 = 0.f, q1 = 0.f, q2 = 0.f, q3 = 0.f;
    #pragma unroll 4
    for (int d = 0; d < 256; d += 4) {
      q0 = fmaf(mem_s[d + 0], Wh1[(d + 0) * 128 + m], q0);
      q1 = fmaf(mem_s[d + 1], Wh1[(d + 1) * 128 + m], q1);
      q2 = fmaf(mem_s[d + 2], Wh1[(d + 2) * 128 + m], q2);
      q3 = fmaf(mem_s[d + 3], Wh1[(d + 3) * 128 + m], q3);
    }
    qv = bh1[m] + ((q0 + q1) + (q2 + q3));
  }
  const float qmu = block_sum256(m < 128 ? qv : 0.f, red) * (1.f / 128.f);
  const float qd = qv - qmu;
  const float qvar = block_sum256(m < 128 ? qd * qd : 0.f, red) * (1.f / 128.f);
  if (m < 128)
    t3_s[m] = gelu_f(qd * rsqrtf(qvar + 1e-5f) * ln_h_g[m] + ln_h_b[m]);
  __syncthreads();

  // h = gelu(t3 @ Wh2 + bh2) (64) -> bf16
  if (m < 64) {
    float h0 = 0.f, h1 = 0.f;
    #pragma unroll 4
    for (int d = 0; d < 128; d += 2) {
      h0 = fmaf(t3_s[d + 0], Wh2[(d + 0) * 64 + m], h0);
      h1 = fmaf(t3_s[d + 1], Wh2[(d + 1) * 64 + m], h1);
    }
    hout[b * 64 + m] = f2bf(gelu_f(bh2[m] + h0 + h1));
  }
}

// K3 (MFMA): out[b,l,k] = tanh(sum_d h[b,d]*W[l,d,k] + bias[l,k])
// GEMM: D[k, b] = A(=W^T)[k, d] @ B(=h^T)[d, b], K=64, mfma_f32_16x16x32_bf16.
// XCD-chunked swizzle (bijective: 6144 = 8*768, ADD not OR): consecutive
// blocks on one XCD share (mat,l) and walk kt sequentially -> per-XCD L2
// sees one l-slab at a time -> HBM page locality for both W reads and
// out writes.
__global__ __launch_bounds__(256, 4) void k_lora(
    const float* __restrict__ WA, const float* __restrict__ bA,
    const float* __restrict__ WB, const float* __restrict__ bB,
    const unsigned short* __restrict__ hb, float* __restrict__ out) {
  __shared__ f32x4 xp[64 * 33];         // 33.8 KB: [b_row][k_chunk], stride 33
  const int t = threadIdx.x;
  const int lane = t & 63;
  const int w = t >> 6;
  const int i = lane & 15;              // A-row (k) / B-col (b) index
  const int g = lane >> 4;              // k-dim group: d = 8g + j
  // XCD-chunked bijective swizzle (6144 = 8 * 768; orig%8 == XCD id)
  const int orig = blockIdx.x;
  const int bid = (orig & 7) * 768 + (orig >> 3);
  const int kt = bid & 127;             // 128 k-tiles of 128
  const int l = (bid >> 7) % 24;
  const int mat = bid / 3072;           // 0 = A, 1 = B
  const float* __restrict__ W = mat ? WB : WA;
  const float* __restrict__ bias = mat ? bB : bA;
  const int kb_blk = kt * 128;          // block's k base (128 wide)
  const int kb = kb_blk + w * 32;       // wave's k base (32 wide)

  const float* Wl = W + (size_t)l * (64 * 16384);

  // A fragments afr[ks][dc]: A[k = kb + ks*16 + i][d = dc*32 + 8g + j] = W[d][k]
  short8b afr[2][2];
  #pragma unroll
  for (int ks = 0; ks < 2; ++ks) {
    #pragma unroll
    for (int dc = 0; dc < 2; ++dc) {
      const float* p = Wl + (size_t)(dc * 32 + 8 * g) * 16384 + kb + ks * 16 + i;
      #pragma unroll
      for (int j = 0; j < 8; ++j)
        afr[ks][dc][j] = (short)f2bf(p[(size_t)j * 16384]);
    }
  }

  // bias (per-k, broadcast over b); hoisted across passes
  f32x4 bv[2];
  #pragma unroll
  for (int ks = 0; ks < 2; ++ks)
    bv[ks] = *(const f32x4*)(bias + (size_t)l * 16384 + kb + ks * 16 + g * 4);

  // store-phase indexing
  const int kc = lane & 31;             // k chunk 0..31 (whole block k-extent)
  const int rsub = lane >> 5;           // 0/1: row within pair

  #pragma unroll
  for (int p = 0; p < 2; ++p) {
    // ---- compute pass p: b in [p*64, p*64+64) ----
    f32x4 acc[2][4];
    #pragma unroll
    for (int ks = 0; ks < 2; ++ks)
      #pragma unroll
      for (int bs = 0; bs < 4; ++bs) acc[ks][bs] = bv[ks];

    #pragma unroll
    for (int bs = 0; bs < 4; ++bs) {
      const unsigned short* hp = hb + (p * 64 + bs * 16 + i) * 64 + 8 * g;
      short8b b0 = *(const short8b*)(hp);        // d = 8g..8g+7
      short8b b1 = *(const short8b*)(hp + 32);   // d = 32 + 8g..
      #pragma unroll
      for (int ks = 0; ks < 2; ++ks) {
        acc[ks][bs] = __builtin_amdgcn_mfma_f32_16x16x32_bf16(afr[ks][0], b0,
                                                              acc[ks][bs], 0, 0, 0);
        acc[ks][bs] = __builtin_amdgcn_mfma_f32_16x16x32_bf16(afr[ks][1], b1,
                                                              acc[ks][bs], 0, 0, 0);
      }
    }

    // ---- epilogue pass p ----
    __syncthreads();                    // buffer free (prev pass reads done)
    #pragma unroll
    for (int ks = 0; ks < 2; ++ks) {
      #pragma unroll
      for (int bs = 0; bs < 4; ++bs) {
        f32x4 o;
        #pragma unroll
        for (int r = 0; r < 4; ++r) o[r] = tanh_f(acc[ks][bs][r]);
        // row = bs*16 + i (0..63), chunk = w*8 + ks*4 + g (0..31)
        xp[(bs * 16 + i) * 33 + (w * 8 + ks * 4 + g)] = o;
      }
    }
    __syncthreads();
    // read + store: wave w handles rows [w*16, w*16+16), 2 rows per instr,
    // each 32-lane half writes 512 B contiguous (kc*16B within the row).
    #pragma unroll
    for (int j = 0; j < 8; ++j) {
      const int row = w * 16 + 2 * j + rsub;
      f32x4 v = xp[row * 33 + kc];
      const size_t b_glob = (size_t)(p * 64 + row);
      float* op = out + (size_t)mat * AB_ELEMS + b_glob * (24 * 16384) +
                  (size_t)l * 16384 + kb_blk + kc * 4;
      __builtin_nontemporal_store(v, (f32x4*)op);
    }
  }
}

extern "C" void kernel_launch(void* const* d_in, const int* in_sizes, int n_in,
                              void* d_out, int out_size, void* d_ws, size_t ws_size,
                              hipStream_t stream) {
  const float* pogt   = (const float*)d_in[0];
  const float* We     = (const float*)d_in[1];
  const float* be     = (const float*)d_in[2];
  const float* ln_e_g = (const float*)d_in[3];
  const float* ln_e_b = (const float*)d_in[4];
  const float* Wp1    = (const float*)d_in[5];
  const float* bp1    = (const float*)d_in[6];
  const float* Wp2    = (const float*)d_in[7];
  const float* bp2    = (const float*)d_in[8];
  // d_in[9] = Wg1 — unused (memory == 0 so memory@Wg1 == 0)
  const float* bg1    = (const float*)d_in[10];
  const float* ln_g_g = (const float*)d_in[11];
  const float* ln_g_b = (const float*)d_in[12];
  const float* Wg2    = (const float*)d_in[13];
  const float* bg2    = (const float*)d_in[14];
  const float* Wh1    = (const float*)d_in[15];
  const float* bh1    = (const float*)d_in[16];
  const float* ln_h_g = (const float*)d_in[17];
  const float* ln_h_b = (const float*)d_in[18];
  const float* Wh2    = (const float*)d_in[19];
  const float* bh2    = (const float*)d_in[20];
  const float* WA     = (const float*)d_in[21];
  const float* bA     = (const float*)d_in[22];
  const float* WB     = (const float*)d_in[23];
  const float* bB     = (const float*)d_in[24];

  float* out = (float*)d_out;
  float* enc_tok = (float*)d_ws;                            // 8 MB
  unsigned short* hbuf = (unsigned short*)((char*)d_ws + 8388608);  // 16 KB bf16
  float* mem_out = out + 2 * AB_ELEMS;                      // [128,256] tail of d_out

  k_encoder<<<2048, 256, 0, stream>>>(pogt, We, be, ln_e_g, ln_e_b, enc_tok);
  k_small<<<128, 256, 0, stream>>>(enc_tok, Wp1, bp1, Wp2, bp2, bg1, ln_g_g,
                                   ln_g_b, Wg2, bg2, Wh1, bh1, ln_h_g, ln_h_b,
                                   Wh2, bh2, mem_out, hbuf);
  k_lora<<<6144, 256, 0, stream>>>(WA, bA, WB, bB, hbuf, out);
}